// Round 3
// baseline (143.276 us; speedup 1.0000x reference)
//
#include <hip/hip_runtime.h>
#include <stdint.h>

#define NPTS 32768
#define NCEN 512
#define DIM  128
#define TOPK 10

#define BM 128
#define BN 128
#define LDT 132   // padded LDS row width (floats): conflict-free b128 reads

// ---------------- numpy pairwise_sum(v*v) over n=128, bit-exact ----------------
// numpy (n <= PW_BLOCKSIZE=128): 8 chains r_j = sum_{b} fl(a[8b+j]^2), b ascending,
// then ((r0+r1)+(r2+r3))+((r4+r5)+(r6+r7)). Products rounded separately (no FMA).
__global__ __launch_bounds__(256) void np_rownorm(const float* __restrict__ src,
                                                  float* __restrict__ dst, int nrows) {
  const int t = threadIdx.x;
  const int lane = t & 63;
  const int wv = t >> 6;
  const int g = lane >> 3;      // row within wave (0..7)
  const int j = lane & 7;       // chain index (0..7)
  const int row = blockIdx.x * 32 + wv * 8 + g;
  if (row >= nrows) return;
  const float* p = src + (size_t)row * DIM;

  float v = p[j];
  float r = __fmul_rn(v, v);
#pragma unroll
  for (int b = 1; b < 16; ++b) {
    v = p[8 * b + j];
    r = __fadd_rn(r, __fmul_rn(v, v));
  }
  // combine: butterfly xor 1,2,4 reproduces ((r0+r1)+(r2+r3))+((r4+r5)+(r6+r7))
  r = __fadd_rn(r, __shfl_xor(r, 1, 64));
  r = __fadd_rn(r, __shfl_xor(r, 2, 64));
  r = __fadd_rn(r, __shfl_xor(r, 4, 64));
  if (j == 0) dst[row] = r;
}

// ---------------- distance GEMM, numpy-exact ----------------
// m_ij = sequential k=0..127 FMA chain (BLAS microkernel semantics);
// d = sqrtf(fmaxf(fl(fl(x2 - 2m) + c2), 0))
__global__ __launch_bounds__(256) void dist_kernel(const float* __restrict__ x,
                                                   const float* __restrict__ cen,
                                                   const float* __restrict__ x2,
                                                   const float* __restrict__ c2,
                                                   float* __restrict__ dist) {
  __shared__ float xT[DIM][LDT];   // xT[k][p]
  __shared__ float cT[DIM][LDT];   // cT[k][c]

  const int t  = threadIdx.x;
  const int pb = blockIdx.y * BM;
  const int cb = blockIdx.x * BN;

  {
    const int p  = t & 127;
    const int kb = (t >> 7) * 64;
    const float4* srcx = (const float4*)&x[(size_t)(pb + p) * DIM + kb];
    const float4* srcc = (const float4*)&cen[(size_t)(cb + p) * DIM + kb];
#pragma unroll
    for (int i = 0; i < 16; ++i) {
      float4 v = srcx[i];
      int k = kb + i * 4;
      xT[k + 0][p] = v.x; xT[k + 1][p] = v.y; xT[k + 2][p] = v.z; xT[k + 3][p] = v.w;
    }
#pragma unroll
    for (int i = 0; i < 16; ++i) {
      float4 v = srcc[i];
      int k = kb + i * 4;
      cT[k + 0][p] = v.x; cT[k + 1][p] = v.y; cT[k + 2][p] = v.z; cT[k + 3][p] = v.w;
    }
  }
  __syncthreads();

  const int wid  = t >> 6;
  const int lane = t & 63;
  const int wr = wid >> 1, wc = wid & 1;
  const int r = lane & 7, c = lane >> 3;
  const int px = wr * 64 + 4 * r;
  const int cx = wc * 64 + 4 * c;

  float acc[8][8];
#pragma unroll
  for (int i = 0; i < 8; ++i)
#pragma unroll
    for (int j = 0; j < 8; ++j) acc[i][j] = 0.f;

#pragma unroll 4
  for (int k = 0; k < DIM; ++k) {   // k ascending: BLAS accumulation order
    float4 xa = *(const float4*)&xT[k][px];
    float4 xb = *(const float4*)&xT[k][px + 32];
    float4 ca = *(const float4*)&cT[k][cx];
    float4 cbv = *(const float4*)&cT[k][cx + 32];
    float xv[8] = {xa.x, xa.y, xa.z, xa.w, xb.x, xb.y, xb.z, xb.w};
    float cv[8] = {ca.x, ca.y, ca.z, ca.w, cbv.x, cbv.y, cbv.z, cbv.w};
#pragma unroll
    for (int i = 0; i < 8; ++i)
#pragma unroll
      for (int j = 0; j < 8; ++j)
        acc[i][j] = __fmaf_rn(xv[i], cv[j], acc[i][j]);
  }

#pragma unroll
  for (int i = 0; i < 8; ++i) {
    const int pt = px + (i & 3) + (i >> 2) * 32;
    const int p  = pb + pt;
    const float xx = x2[p];
#pragma unroll
    for (int jq = 0; jq < 2; ++jq) {
      const int cg = cb + cx + jq * 32;
      float4 cc = *(const float4*)&c2[cg];
      // fl(x2 - 2m): single rounding == fmaf(-2, m, x2); then separate rounded +c2
      float t0 = __fmaf_rn(-2.f, acc[i][jq * 4 + 0], xx);
      float t1 = __fmaf_rn(-2.f, acc[i][jq * 4 + 1], xx);
      float t2 = __fmaf_rn(-2.f, acc[i][jq * 4 + 2], xx);
      float t3 = __fmaf_rn(-2.f, acc[i][jq * 4 + 3], xx);
      float4 o;
      o.x = sqrtf(fmaxf(__fadd_rn(t0, cc.x), 0.f));
      o.y = sqrtf(fmaxf(__fadd_rn(t1, cc.y), 0.f));
      o.z = sqrtf(fmaxf(__fadd_rn(t2, cc.z), 0.f));
      o.w = sqrtf(fmaxf(__fadd_rn(t3, cc.w), 0.f));
      *(float4*)&dist[(size_t)p * NCEN + cg] = o;
    }
  }
}

// ---------------- top-10 by (dist, idx) lexicographic + gather ----------------
__global__ __launch_bounds__(256) void topk_gather_kernel(const float* __restrict__ dist,
                                                          const float* __restrict__ x,
                                                          float* __restrict__ out) {
  const int p    = blockIdx.x * 4 + (threadIdx.x >> 6);
  const int lane = threadIdx.x & 63;

  const float4* dp = (const float4*)(dist + (size_t)p * NCEN);
  float4 va = dp[lane];
  float4 vb = dp[lane + 64];

  // d >= 0 so raw f32 bits order == value order; (d_bits<<32)|idx -> stable ties
  unsigned long long key[8];
  {
    const unsigned ca = 4u * lane, cb = 256u + 4u * lane;
    key[0] = ((unsigned long long)__float_as_uint(va.x) << 32) | (ca + 0);
    key[1] = ((unsigned long long)__float_as_uint(va.y) << 32) | (ca + 1);
    key[2] = ((unsigned long long)__float_as_uint(va.z) << 32) | (ca + 2);
    key[3] = ((unsigned long long)__float_as_uint(va.w) << 32) | (ca + 3);
    key[4] = ((unsigned long long)__float_as_uint(vb.x) << 32) | (cb + 0);
    key[5] = ((unsigned long long)__float_as_uint(vb.y) << 32) | (cb + 1);
    key[6] = ((unsigned long long)__float_as_uint(vb.z) << 32) | (cb + 2);
    key[7] = ((unsigned long long)__float_as_uint(vb.w) << 32) | (cb + 3);
  }

  float* op = out + (size_t)p * TOPK * DIM;

#pragma unroll
  for (int t = 0; t < TOPK; ++t) {
    unsigned long long m = key[0];
#pragma unroll
    for (int s = 1; s < 8; ++s) m = (key[s] < m) ? key[s] : m;
#pragma unroll
    for (int off = 32; off > 0; off >>= 1) {
      unsigned long long o = __shfl_xor(m, off, 64);
      m = (o < m) ? o : m;
    }
#pragma unroll
    for (int s = 0; s < 8; ++s)
      if (key[s] == m) key[s] = ~0ull;

    const int idx = (int)(m & 0x1ffull);
    float2 v = *(const float2*)&x[(size_t)idx * DIM + 2 * lane];
    *(float2*)&op[(size_t)t * DIM + 2 * lane] = v;
  }
}

extern "C" void kernel_launch(void* const* d_in, const int* in_sizes, int n_in,
                              void* d_out, int out_size, void* d_ws, size_t ws_size,
                              hipStream_t stream) {
  const float* x   = (const float*)d_in[0];
  const float* cen = (const float*)d_in[1];
  float* out = (float*)d_out;

  // ws layout: [c2: 2KB pad->4KB][x2: 128KB][dist: 64MB]
  float* c2   = (float*)d_ws;
  float* x2   = (float*)((char*)d_ws + 4096);
  float* dist = (float*)((char*)d_ws + 4096 + 131072);

  np_rownorm<<<NCEN / 32, 256, 0, stream>>>(cen, c2, NCEN);
  np_rownorm<<<NPTS / 32, 256, 0, stream>>>(x, x2, NPTS);
  dist_kernel<<<dim3(NCEN / BN, NPTS / BM), 256, 0, stream>>>(x, cen, x2, c2, dist);
  topk_gather_kernel<<<NPTS / 4, 256, 0, stream>>>(dist, x, out);
}

// Round 4
// 123.624 us; speedup vs baseline: 1.1590x; 1.1590x over previous
//
#include <hip/hip_runtime.h>
#include <stdint.h>

#define NPTS 32768
#define NCEN 512
#define DIM  128
#define TOPK 10

#define BM 128
#define BN 128
#define KSTEP 32
#define LDT 132   // padded LDS row width (floats): conflict-free b128 reads

// ---------------- numpy pairwise_sum(v*v) over n=128, bit-exact ----------------
// numpy (n <= PW_BLOCKSIZE=128): 8 chains r_j = sum_b fl(a[8b+j]^2), b ascending,
// then ((r0+r1)+(r2+r3))+((r4+r5)+(r6+r7)). Products rounded separately (no FMA).
__global__ __launch_bounds__(256) void np_rownorm(const float* __restrict__ src,
                                                  float* __restrict__ dst, int nrows) {
  const int t = threadIdx.x;
  const int lane = t & 63;
  const int wv = t >> 6;
  const int g = lane >> 3;      // row within wave (0..7)
  const int j = lane & 7;       // chain index (0..7)
  const int row = blockIdx.x * 32 + wv * 8 + g;
  if (row >= nrows) return;
  const float* p = src + (size_t)row * DIM;

  float v = p[j];
  float r = __fmul_rn(v, v);
#pragma unroll
  for (int b = 1; b < 16; ++b) {
    v = p[8 * b + j];
    r = __fadd_rn(r, __fmul_rn(v, v));
  }
  r = __fadd_rn(r, __shfl_xor(r, 1, 64));
  r = __fadd_rn(r, __shfl_xor(r, 2, 64));
  r = __fadd_rn(r, __shfl_xor(r, 4, 64));
  if (j == 0) dst[row] = r;
}

// ---------------- distance GEMM, numpy-exact, occupancy-tuned ----------------
// KSTEP=32 single LDS buffer (33.8 KB) -> 4 blocks/CU (16 waves/CU).
// acc registers carry across k-steps: identical sequential k=0..127 FMA chain.
__global__ __launch_bounds__(256, 4) void dist_kernel(const float* __restrict__ x,
                                                      const float* __restrict__ cen,
                                                      const float* __restrict__ x2,
                                                      const float* __restrict__ c2,
                                                      float* __restrict__ dist) {
  __shared__ float xT[KSTEP][LDT];   // xT[k][p]
  __shared__ float cT[KSTEP][LDT];   // cT[k][c]

  const int t  = threadIdx.x;
  const int pb = blockIdx.y * BM;
  const int cb = blockIdx.x * BN;

  const int srow = t & 127;          // staged row (point or center)
  const int kh   = (t >> 7) * 16;    // k-half within step

  const int wid  = t >> 6;
  const int lane = t & 63;
  const int wr = wid >> 1, wc = wid & 1;
  const int r = lane & 7, c = lane >> 3;
  const int px = wr * 64 + 4 * r;
  const int cx = wc * 64 + 4 * c;

  float acc[8][8];
#pragma unroll
  for (int i = 0; i < 8; ++i)
#pragma unroll
    for (int j = 0; j < 8; ++j) acc[i][j] = 0.f;

  for (int s = 0; s < DIM / KSTEP; ++s) {
    if (s) __syncthreads();
    // stage this k-step's tiles, transposed
    {
      const float4* srcx = (const float4*)&x[(size_t)(pb + srow) * DIM + s * KSTEP + kh];
      const float4* srcc = (const float4*)&cen[(size_t)(cb + srow) * DIM + s * KSTEP + kh];
#pragma unroll
      for (int i = 0; i < 4; ++i) {
        float4 v = srcx[i];
        int k = kh + i * 4;
        xT[k + 0][srow] = v.x; xT[k + 1][srow] = v.y; xT[k + 2][srow] = v.z; xT[k + 3][srow] = v.w;
      }
#pragma unroll
      for (int i = 0; i < 4; ++i) {
        float4 v = srcc[i];
        int k = kh + i * 4;
        cT[k + 0][srow] = v.x; cT[k + 1][srow] = v.y; cT[k + 2][srow] = v.z; cT[k + 3][srow] = v.w;
      }
    }
    __syncthreads();

#pragma unroll 4
    for (int kk = 0; kk < KSTEP; ++kk) {
      float4 xa  = *(const float4*)&xT[kk][px];
      float4 xb  = *(const float4*)&xT[kk][px + 32];
      float4 ca  = *(const float4*)&cT[kk][cx];
      float4 cbv = *(const float4*)&cT[kk][cx + 32];
      float xv[8] = {xa.x, xa.y, xa.z, xa.w, xb.x, xb.y, xb.z, xb.w};
      float cv[8] = {ca.x, ca.y, ca.z, ca.w, cbv.x, cbv.y, cbv.z, cbv.w};
#pragma unroll
      for (int i = 0; i < 8; ++i)
#pragma unroll
        for (int j = 0; j < 8; ++j)
          acc[i][j] = __fmaf_rn(xv[i], cv[j], acc[i][j]);
    }
  }

  // epilogue: d = sqrt(max(fl(fl(x2 - 2m) + c2), 0))
#pragma unroll
  for (int i = 0; i < 8; ++i) {
    const int pt = px + (i & 3) + (i >> 2) * 32;
    const int p  = pb + pt;
    const float xx = x2[p];
#pragma unroll
    for (int jq = 0; jq < 2; ++jq) {
      const int cg = cb + cx + jq * 32;
      float4 cc = *(const float4*)&c2[cg];
      float t0 = __fmaf_rn(-2.f, acc[i][jq * 4 + 0], xx);
      float t1 = __fmaf_rn(-2.f, acc[i][jq * 4 + 1], xx);
      float t2 = __fmaf_rn(-2.f, acc[i][jq * 4 + 2], xx);
      float t3 = __fmaf_rn(-2.f, acc[i][jq * 4 + 3], xx);
      float4 o;
      o.x = sqrtf(fmaxf(__fadd_rn(t0, cc.x), 0.f));
      o.y = sqrtf(fmaxf(__fadd_rn(t1, cc.y), 0.f));
      o.z = sqrtf(fmaxf(__fadd_rn(t2, cc.z), 0.f));
      o.w = sqrtf(fmaxf(__fadd_rn(t3, cc.w), 0.f));
      *(float4*)&dist[(size_t)p * NCEN + cg] = o;
    }
  }
}

// ---------------- top-10 by (dist, idx) lexicographic + gather ----------------
__global__ __launch_bounds__(256) void topk_gather_kernel(const float* __restrict__ dist,
                                                          const float* __restrict__ x,
                                                          float* __restrict__ out) {
  const int p    = blockIdx.x * 4 + (threadIdx.x >> 6);
  const int lane = threadIdx.x & 63;

  const float4* dp = (const float4*)(dist + (size_t)p * NCEN);
  float4 va = dp[lane];
  float4 vb = dp[lane + 64];

  // d >= 0 so raw f32 bits order == value order; (d_bits<<32)|idx -> stable ties
  unsigned long long key[8];
  {
    const unsigned ca = 4u * lane, cb = 256u + 4u * lane;
    key[0] = ((unsigned long long)__float_as_uint(va.x) << 32) | (ca + 0);
    key[1] = ((unsigned long long)__float_as_uint(va.y) << 32) | (ca + 1);
    key[2] = ((unsigned long long)__float_as_uint(va.z) << 32) | (ca + 2);
    key[3] = ((unsigned long long)__float_as_uint(va.w) << 32) | (ca + 3);
    key[4] = ((unsigned long long)__float_as_uint(vb.x) << 32) | (cb + 0);
    key[5] = ((unsigned long long)__float_as_uint(vb.y) << 32) | (cb + 1);
    key[6] = ((unsigned long long)__float_as_uint(vb.z) << 32) | (cb + 2);
    key[7] = ((unsigned long long)__float_as_uint(vb.w) << 32) | (cb + 3);
  }

  float* op = out + (size_t)p * TOPK * DIM;

#pragma unroll
  for (int t = 0; t < TOPK; ++t) {
    unsigned long long m = key[0];
#pragma unroll
    for (int s = 1; s < 8; ++s) m = (key[s] < m) ? key[s] : m;
#pragma unroll
    for (int off = 32; off > 0; off >>= 1) {
      unsigned long long o = __shfl_xor(m, off, 64);
      m = (o < m) ? o : m;
    }
#pragma unroll
    for (int s = 0; s < 8; ++s)
      if (key[s] == m) key[s] = ~0ull;

    const int idx = (int)(m & 0x1ffull);
    float2 v = *(const float2*)&x[(size_t)idx * DIM + 2 * lane];
    *(float2*)&op[(size_t)t * DIM + 2 * lane] = v;
  }
}

extern "C" void kernel_launch(void* const* d_in, const int* in_sizes, int n_in,
                              void* d_out, int out_size, void* d_ws, size_t ws_size,
                              hipStream_t stream) {
  const float* x   = (const float*)d_in[0];
  const float* cen = (const float*)d_in[1];
  float* out = (float*)d_out;

  // ws layout: [c2: 2KB pad->4KB][x2: 128KB][dist: 64MB]
  float* c2   = (float*)d_ws;
  float* x2   = (float*)((char*)d_ws + 4096);
  float* dist = (float*)((char*)d_ws + 4096 + 131072);

  np_rownorm<<<NCEN / 32, 256, 0, stream>>>(cen, c2, NCEN);
  np_rownorm<<<NPTS / 32, 256, 0, stream>>>(x, x2, NPTS);
  dist_kernel<<<dim3(NCEN / BN, NPTS / BM), 256, 0, stream>>>(x, cen, x2, c2, dist);
  topk_gather_kernel<<<NPTS / 4, 256, 0, stream>>>(dist, x, out);
}